// Round 5
// baseline (1640.708 us; speedup 1.0000x reference)
//
#include <hip/hip_runtime.h>
#include <cstddef>

#define NXS 64
#define NUS 32
#define NYS 32
#define NWS 64
#define BBATCH 256
#define TT  2048

// ws layout: G[160][192] col-major-by-output: G[c*192 + k]
//   output cols c: [0,64) -> w'(z, tanh applied), [64,128) -> x', [128,160) -> y
//   input dims  k: [0,64) x, [64,128) w, [128,160) u_t, [160,192) u_{t+1}
// Size = 30720 floats (same footprint as all prior rounds' ws usage).

typedef float v2f __attribute__((ext_vector_type(2)));

__device__ __forceinline__ float fast_tanh(float x) {
    float e = __expf(2.0f * x);
    return 1.0f - 2.0f * __builtin_amdgcn_rcpf(e + 1.0f);
}

template<int CTRL>
__device__ __forceinline__ float dpp_add(float v) {
    int t = __builtin_amdgcn_update_dpp(0, __float_as_int(v), CTRL, 0xF, 0xF, true);
    return v + __int_as_float(t);
}

// barrier draining only LDS (global loads/stores stay in flight)
__device__ __forceinline__ void step_barrier() {
    asm volatile("s_waitcnt lgkmcnt(0)\n\ts_barrier" ::: "memory");
}

// ---------------------------------------------------------------------------
// One-shot setup: Gauss-Jordan Yinv (LDS) -> Wxtile = [A;B1;B2]~@Yinv (LDS)
// -> G (global ws). Single block, 1024 threads.
__global__ __launch_bounds__(1024) void setup_g_kernel(const float* __restrict__ Y,
                                                       const float* __restrict__ lam,
                                                       const float* __restrict__ A,
                                                       const float* __restrict__ B1,
                                                       const float* __restrict__ B2,
                                                       const float* __restrict__ C1,
                                                       const float* __restrict__ D11,
                                                       const float* __restrict__ D12,
                                                       const float* __restrict__ C2,
                                                       const float* __restrict__ D21,
                                                       float* __restrict__ ws) {
    __shared__ float M[64 * 129];
    __shared__ float rowk[128];
    __shared__ float ck[64];
    __shared__ float WxT[160 * 64];   // rows: 0..63 A-part, 64..95 B1-part, 96..159 B2-part
    const int tid = threadIdx.x;

    for (int idx = tid; idx < 64 * 64; idx += 1024) {
        int r = idx >> 6, c = idx & 63;
        M[r * 129 + c]      = Y[idx];
        M[r * 129 + 64 + c] = (r == c) ? 1.0f : 0.0f;
    }
    __syncthreads();

    for (int k = 0; k < 64; ++k) {
        float dv = 1.0f / M[k * 129 + k];
        if (tid < 128) rowk[tid] = M[k * 129 + tid] * dv;
        if (tid >= 128 && tid < 192) ck[tid - 128] = M[(tid - 128) * 129 + k];
        __syncthreads();
        for (int idx = tid; idx < 64 * 128; idx += 1024) {
            int r = idx >> 7, c = idx & 127;
            float cur = M[r * 129 + c];
            M[r * 129 + c] = (r == k) ? rowk[c] : cur - ck[r] * rowk[c];
        }
        __syncthreads();
    }
    // Yinv[m][j] = M[m*129 + 64 + j]

    for (int idx = tid; idx < 160 * 64; idx += 1024) {
        int k = idx >> 6, j = idx & 63;
        float s = 0.0f;
        if (k < 64) {
            #pragma unroll 8
            for (int m = 0; m < 64; ++m) s += A[m * 64 + k] * M[m * 129 + 64 + j];
        } else if (k < 96) {
            int ku = k - 64;
            #pragma unroll 8
            for (int m = 0; m < 64; ++m) s += B1[m * 32 + ku] * M[m * 129 + 64 + j];
        } else {
            int kw = k - 96;
            #pragma unroll 8
            for (int m = 0; m < 64; ++m) s += B2[m * 64 + kw] * M[m * 129 + 64 + j];
        }
        WxT[k * 64 + j] = s;
    }
    __syncthreads();

    // G: for state-dim k (scan layout), Wxtile row map:
    //   k<64 (x) -> k ; k in [64,128) (w) -> 96+(k-64) ; k in [128,160) (u_t) -> 64+(k-128)
    for (int idx = tid; idx < 160 * 192; idx += 1024) {
        int c = idx / 192;
        int k = idx - c * 192;
        float v;
        if (c < 64) {                         // w'-col: z_{t+1} row, scaled 1/lam
            if (k < 160) {
                int km = (k < 64) ? k : (k < 128) ? (96 + k - 64) : (64 + k - 128);
                float s = 0.0f;
                #pragma unroll 8
                for (int m = 0; m < 64; ++m) s += WxT[km * 64 + m] * C2[c * 64 + m];
                v = s / lam[c];
            } else {
                v = D21[c * 32 + (k - 160)] / lam[c];
            }
        } else if (c < 128) {                 // x'-col
            int j = c - 64;
            if (k < 160) {
                int km = (k < 64) ? k : (k < 128) ? (96 + k - 64) : (64 + k - 128);
                v = WxT[km * 64 + j];
            } else v = 0.0f;
        } else {                              // y-col
            int j = c - 128;
            v = (k < 64)  ? C1[j * 64 + k]
              : (k < 128) ? D12[j * 64 + (k - 64)]
              : (k < 160) ? D11[j * 32 + (k - 128)]
                          : 0.0f;
        }
        ws[c * 192 + k] = v;
    }
}

// ---------------------------------------------------------------------------
// Scan v5: 1 chain/block, 128 threads (2 waves). Lane l: quad q=l&3 owns
// K-quarter; group g=l>>2 owns output cols 5g..5g+4 (R=5, weights in VGPRs).
// Per step: 8 state ds_read_b128 (quad-rotated slots -> 4 distinct banksets,
// conflict-free) + 4 u ds_read_b128; 120 pk-FMA; quad all-reduce = 2 DPP/col;
// writer lanes (q==r, q==0 also r=4) apply tanh / write state / batch y.
// u lives in a 32-slot LDS ring; 1 global float4/lane per 16 steps, landing
// slots (cur+8..cur+23) & 31 -- never the slots read this step.
__global__ __launch_bounds__(128, 1) void rnn5_kernel(const float* __restrict__ xp,
                                                      const float* __restrict__ ws,
                                                      float* __restrict__ out) {
    const int b  = blockIdx.x;
    const int l  = threadIdx.x;
    const int q  = l & 3;
    const int g  = l >> 2;
    const int c0 = 5 * g;

    __shared__ __align__(16) float sbuf[2][128];
    __shared__ __align__(16) float uRs[32][32];

    const float4* __restrict__ xp4 = (const float4*)(xp + (size_t)b * (TT * NUS));
    const size_t yb   = (size_t)b * (TT * NYS);
    const size_t xoff = (size_t)BBATCH * TT * NYS;

    // ---- weights: 5 cols x 48 floats, ordered to match runtime read order --
    v2f wst[5][16];   // state part (k<128), quad-rotated b128 order
    v2f wu[5][8];     // u part: [0..3]=u_t quarter, [4..7]=u_{t+1} quarter
    #pragma unroll
    for (int r = 0; r < 5; ++r) {
        const float* Gc = ws + (size_t)(c0 + r) * 192;
        #pragma unroll
        for (int j = 0; j < 8; ++j) {
            int m = (j + 2 * q) & 7;
            float4 gv = *(const float4*)(Gc + 32 * q + 4 * m);
            wst[r][2 * j]     = (v2f){gv.x, gv.y};
            wst[r][2 * j + 1] = (v2f){gv.z, gv.w};
        }
        #pragma unroll
        for (int t = 0; t < 4; ++t) {
            int k = (t < 2) ? (128 + 8 * q + 4 * t) : (160 + 8 * q + 4 * (t - 2));
            float4 gv = *(const float4*)(Gc + k);
            wu[r][2 * t]     = (v2f){gv.x, gv.y};
            wu[r][2 * t + 1] = (v2f){gv.z, gv.w};
        }
    }

    // ---- preload u_0..u_30 (slot 31 zeroed; refreshed by ring before use) --
    #pragma unroll
    for (int t = 0; t < 2; ++t) {
        int idx = l + 128 * t;
        int s = idx >> 3, q8 = idx & 7;
        float4 v = make_float4(0.f, 0.f, 0.f, 0.f);
        if (s < 31) v = xp4[s * 8 + q8];
        *(float4*)&uRs[s][q8 * 4] = v;
    }
    __syncthreads();

    // ---- prologue (step -1): state = 0, so only u_0 (u_cur) contributes ----
    {
        const float4* u1 = (const float4*)&uRs[0][0];
        float4 uv2 = u1[q * 2], uv3 = u1[q * 2 + 1];
        float sr[5];
        #pragma unroll
        for (int r = 0; r < 5; ++r) {
            v2f a0 = (v2f){uv2.x, uv2.y} * wu[r][4] + (v2f){uv3.x, uv3.y} * wu[r][6];
            v2f a1 = (v2f){uv2.z, uv2.w} * wu[r][5] + (v2f){uv3.z, uv3.w} * wu[r][7];
            v2f a = a0 + a1;
            float s = a.x + a.y;
            s = dpp_add<0xB1>(s);
            s = dpp_add<0x4E>(s);
            sr[r] = s;
        }
        float sA = (q == 1) ? sr[1] : (q == 2) ? sr[2] : (q == 3) ? sr[3] : sr[0];
        int cA = c0 + q;
        if (cA < 64) sbuf[1][64 + cA] = fast_tanh(sA);
        if (q == 0 && c0 + 4 < 64) sbuf[1][64 + c0 + 4] = fast_tanh(sr[4]);
        if (l < 64) sbuf[1][l] = 0.0f;   // x_0 = 0
    }
    step_barrier();

    float4 upref;
    float ybA[8], ybB[8];

    #pragma unroll 8
    for (int i = 0; i < TT; ++i) {
        const int rp = (i + 1) & 1, wp = i & 1;
        const int ip = i & 31, ic = (i + 1) & 31;

        if ((i & 15) == 0) {                  // issue loads for u_{i+16..i+31}
            int t = i + 16 + (l >> 3);
            if (t < TT) upref = xp4[t * 8 + (l & 7)];
        }
        if ((i & 15) == 8) {                  // land u_{i+8..i+23}
            int t = i + 8 + (l >> 3);
            if (t < TT) *(float4*)&uRs[t & 31][(l & 7) * 4] = upref;
        }

        const float4* sb4 = (const float4*)&sbuf[rp][0];
        float4 sv[8];
        #pragma unroll
        for (int j = 0; j < 8; ++j) sv[j] = sb4[q * 8 + ((j + 2 * q) & 7)];
        const float4* u0 = (const float4*)&uRs[ip][0];
        const float4* u1 = (const float4*)&uRs[ic][0];
        float4 uv0 = u0[q * 2], uv1 = u0[q * 2 + 1];
        float4 uv2 = u1[q * 2], uv3 = u1[q * 2 + 1];

        float sr[5];
        #pragma unroll
        for (int r = 0; r < 5; ++r) {
            v2f a0 = {0.f, 0.f}, a1 = {0.f, 0.f};
            #pragma unroll
            for (int j = 0; j < 8; ++j) {
                a0 += (v2f){sv[j].x, sv[j].y} * wst[r][2 * j];
                a1 += (v2f){sv[j].z, sv[j].w} * wst[r][2 * j + 1];
            }
            a0 += (v2f){uv0.x, uv0.y} * wu[r][0] + (v2f){uv1.x, uv1.y} * wu[r][2];
            a1 += (v2f){uv0.z, uv0.w} * wu[r][1] + (v2f){uv1.z, uv1.w} * wu[r][3];
            a0 += (v2f){uv2.x, uv2.y} * wu[r][4] + (v2f){uv3.x, uv3.y} * wu[r][6];
            a1 += (v2f){uv2.z, uv2.w} * wu[r][5] + (v2f){uv3.z, uv3.w} * wu[r][7];
            v2f a = a0 + a1;
            float s = a.x + a.y;
            s = dpp_add<0xB1>(s);
            s = dpp_add<0x4E>(s);
            sr[r] = s;
        }

        float sA = (q == 1) ? sr[1] : (q == 2) ? sr[2] : (q == 3) ? sr[3] : sr[0];
        const int cA = c0 + q;
        if (cA < 64) {
            sbuf[wp][64 + cA] = fast_tanh(sA);
        } else if (cA < 128) {
            sbuf[wp][cA - 64] = sA;
            if (i == TT - 1) out[xoff + (size_t)b * 64 + (cA - 64)] = sA;
        } else {
            ybA[i & 7] = sA;
            if ((i & 7) == 7) {
                size_t base = yb + (size_t)(i - 7) * NYS + (cA - 128);
                #pragma unroll
                for (int ss = 0; ss < 8; ++ss) out[base + (size_t)ss * NYS] = ybA[ss];
            }
        }
        if (q == 0) {
            const int cB = c0 + 4;
            float sB = sr[4];
            if (cB < 64) {
                sbuf[wp][64 + cB] = fast_tanh(sB);
            } else if (cB < 128) {
                sbuf[wp][cB - 64] = sB;
                if (i == TT - 1) out[xoff + (size_t)b * 64 + (cB - 64)] = sB;
            } else {
                ybB[i & 7] = sB;
                if ((i & 7) == 7) {
                    size_t base = yb + (size_t)(i - 7) * NYS + (cB - 128);
                    #pragma unroll
                    for (int ss = 0; ss < 8; ++ss) out[base + (size_t)ss * NYS] = ybB[ss];
                }
            }
        }
        step_barrier();
    }
}

// ---------------------------------------------------------------------------
extern "C" void kernel_launch(void* const* d_in, const int* in_sizes, int n_in,
                              void* d_out, int out_size, void* d_ws, size_t ws_size,
                              hipStream_t stream) {
    const float* xp  = (const float*)d_in[0];
    const float* Y   = (const float*)d_in[1];
    const float* lam = (const float*)d_in[2];
    const float* A   = (const float*)d_in[3];
    const float* B1  = (const float*)d_in[4];
    const float* B2  = (const float*)d_in[5];
    const float* C1  = (const float*)d_in[6];
    const float* D11 = (const float*)d_in[7];
    const float* D12 = (const float*)d_in[8];
    const float* C2  = (const float*)d_in[9];
    const float* D21 = (const float*)d_in[10];
    float* out = (float*)d_out;
    float* ws  = (float*)d_ws;

    hipLaunchKernelGGL(setup_g_kernel, dim3(1), dim3(1024), 0, stream,
                       Y, lam, A, B1, B2, C1, D11, D12, C2, D21, ws);
    hipLaunchKernelGGL(rnn5_kernel, dim3(BBATCH), dim3(128), 0, stream, xp, ws, out);
}

// Round 6
// 1097.278 us; speedup vs baseline: 1.4953x; 1.4953x over previous
//
#include <hip/hip_runtime.h>
#include <cstddef>

#define NXS 64
#define NUS 32
#define NYS 32
#define NWS 64
#define BBATCH 256
#define TT  2048

// ws layout: G[160][192] col-major-by-output: G[c*192 + k]
//   output cols c: [0,64) -> w'(z, tanh applied), [64,128) -> x', [128,160) -> y
//   input dims  k: [0,64) x, [64,128) w, [128,160) u_t, [160,192) u_{t+1}
#define SLP 20   // state slice pitch (floats): 8 slices x 16 floats + 4 pad

typedef float v2f __attribute__((ext_vector_type(2)));

__device__ __forceinline__ float fast_tanh(float x) {
    float e = __expf(2.0f * x);
    return 1.0f - 2.0f * __builtin_amdgcn_rcpf(e + 1.0f);
}

template<int CTRL>
__device__ __forceinline__ float dpp_add(float v) {
    int t = __builtin_amdgcn_update_dpp(0, __float_as_int(v), CTRL, 0xF, 0xF, true);
    return v + __int_as_float(t);
}

// barrier draining only LDS (global loads/stores stay in flight)
__device__ __forceinline__ void step_barrier() {
    asm volatile("s_waitcnt lgkmcnt(0)\n\ts_barrier" ::: "memory");
}

// ---------------------------------------------------------------------------
// One-shot setup: Gauss-Jordan Yinv (LDS) -> Wxtile = [A;B1;B2]~@Yinv (LDS)
// -> G (global ws). Single block, 1024 threads.  (verified in round 5)
__global__ __launch_bounds__(1024) void setup_g_kernel(const float* __restrict__ Y,
                                                       const float* __restrict__ lam,
                                                       const float* __restrict__ A,
                                                       const float* __restrict__ B1,
                                                       const float* __restrict__ B2,
                                                       const float* __restrict__ C1,
                                                       const float* __restrict__ D11,
                                                       const float* __restrict__ D12,
                                                       const float* __restrict__ C2,
                                                       const float* __restrict__ D21,
                                                       float* __restrict__ ws) {
    __shared__ float M[64 * 129];
    __shared__ float rowk[128];
    __shared__ float ck[64];
    __shared__ float WxT[160 * 64];   // rows: 0..63 A-part, 64..95 B1-part, 96..159 B2-part
    const int tid = threadIdx.x;

    for (int idx = tid; idx < 64 * 64; idx += 1024) {
        int r = idx >> 6, c = idx & 63;
        M[r * 129 + c]      = Y[idx];
        M[r * 129 + 64 + c] = (r == c) ? 1.0f : 0.0f;
    }
    __syncthreads();

    for (int k = 0; k < 64; ++k) {
        float dv = 1.0f / M[k * 129 + k];
        if (tid < 128) rowk[tid] = M[k * 129 + tid] * dv;
        if (tid >= 128 && tid < 192) ck[tid - 128] = M[(tid - 128) * 129 + k];
        __syncthreads();
        for (int idx = tid; idx < 64 * 128; idx += 1024) {
            int r = idx >> 7, c = idx & 127;
            float cur = M[r * 129 + c];
            M[r * 129 + c] = (r == k) ? rowk[c] : cur - ck[r] * rowk[c];
        }
        __syncthreads();
    }
    // Yinv[m][j] = M[m*129 + 64 + j]

    for (int idx = tid; idx < 160 * 64; idx += 1024) {
        int k = idx >> 6, j = idx & 63;
        float s = 0.0f;
        if (k < 64) {
            #pragma unroll 8
            for (int m = 0; m < 64; ++m) s += A[m * 64 + k] * M[m * 129 + 64 + j];
        } else if (k < 96) {
            int ku = k - 64;
            #pragma unroll 8
            for (int m = 0; m < 64; ++m) s += B1[m * 32 + ku] * M[m * 129 + 64 + j];
        } else {
            int kw = k - 96;
            #pragma unroll 8
            for (int m = 0; m < 64; ++m) s += B2[m * 64 + kw] * M[m * 129 + 64 + j];
        }
        WxT[k * 64 + j] = s;
    }
    __syncthreads();

    // G: state-dim k -> Wxtile row map:
    //   k<64 (x) -> k ; k in [64,128) (w) -> 96+(k-64) ; k in [128,160) (u_t) -> 64+(k-128)
    for (int idx = tid; idx < 160 * 192; idx += 1024) {
        int c = idx / 192;
        int k = idx - c * 192;
        float v;
        if (c < 64) {                         // w'-col: z_{t+1} row, scaled 1/lam
            if (k < 160) {
                int km = (k < 64) ? k : (k < 128) ? (96 + k - 64) : (64 + k - 128);
                float s = 0.0f;
                #pragma unroll 8
                for (int m = 0; m < 64; ++m) s += WxT[km * 64 + m] * C2[c * 64 + m];
                v = s / lam[c];
            } else {
                v = D21[c * 32 + (k - 160)] / lam[c];
            }
        } else if (c < 128) {                 // x'-col
            int j = c - 64;
            if (k < 160) {
                int km = (k < 64) ? k : (k < 128) ? (96 + k - 64) : (64 + k - 128);
                v = WxT[km * 64 + j];
            } else v = 0.0f;
        } else {                              // y-col
            int j = c - 128;
            v = (k < 64)  ? C1[j * 64 + k]
              : (k < 128) ? D12[j * 64 + (k - 64)]
              : (k < 160) ? D11[j * 32 + (k - 128)]
                          : 0.0f;
        }
        ws[c * 192 + k] = v;
    }
}

// ---------------------------------------------------------------------------
// Scan v6: 1 chain/block, 256 threads (4 waves, 1/SIMD -> all 4 SIMDs busy).
// K-split 8: lane e = lane&7 owns dims [16e,16e+16) of [x;w] plus an 8-float
// u chunk (e<4: u_t[8e..], e>=4: u_{t+1}[8(e-4)..]).  Group = 8 lanes
// (wv,g); group id Gq = 8*wv + (lane>>3)&7 in [0,32); outputs c = 32r+Gq,
// r in [0,5): r=0,1 w-cols, r=2,3 x-cols, r=4 y-col.
// Per lane-step: 4 state ds_read_b128 (slice pitch 80B -> bank-group
// (5e+k)&7 = permutation, conflict-free) + 2 u b128 (rows padded to 36
// floats -> +4 banks/row, disjoint), 60 pk-FMA, 3 DPP-adds/output
// (xor1, xor2, half-row mirror = 8-lane all-reduce), 1 predicated ds_write.
// u: 32-slot LDS ring, 1 float4/lane (tid<128) per 16 steps (v5 pattern).
__global__ __launch_bounds__(256, 1) void rnn6_kernel(const float* __restrict__ xp,
                                                      const float* __restrict__ ws,
                                                      float* __restrict__ out) {
    const int b   = blockIdx.x;
    const int tid = threadIdx.x;
    const int l   = tid & 63;
    const int wv  = tid >> 6;
    const int g   = l >> 3;
    const int e   = l & 7;
    const int Gq  = 8 * wv + g;          // output group [0,32)

    __shared__ __align__(16) float sbuf[2][8][SLP];
    __shared__ __align__(16) float uRs[32][36];

    const float4* __restrict__ xp4 = (const float4*)(xp + (size_t)b * (TT * NUS));
    const size_t yb   = (size_t)b * (TT * NYS);
    const size_t xoff = (size_t)BBATCH * TT * NYS;

    // ---- weights: 5 outputs (c = 32r+Gq) x 24 dims (state slice e + u chunk) ----
    v2f wst[5][8], wu4[5][4];
    #pragma unroll
    for (int r = 0; r < 5; ++r) {
        const float* Gc = ws + (size_t)(32 * r + Gq) * 192;
        const float* sb = Gc + 16 * e;
        #pragma unroll
        for (int k = 0; k < 4; ++k) {
            float4 gv = *(const float4*)(sb + 4 * k);
            wst[r][2 * k]     = (v2f){gv.x, gv.y};
            wst[r][2 * k + 1] = (v2f){gv.z, gv.w};
        }
        const float* ub = Gc + ((e < 4) ? (128 + 8 * e) : (160 + 8 * (e - 4)));
        #pragma unroll
        for (int t = 0; t < 2; ++t) {
            float4 gv = *(const float4*)(ub + 4 * t);
            wu4[r][2 * t]     = (v2f){gv.x, gv.y};
            wu4[r][2 * t + 1] = (v2f){gv.z, gv.w};
        }
    }

    // ---- init: u slots 0..30 = u_0..30, slot 31 = 0 (u_{-1}); sbuf[0] = 0 ----
    {
        int s = tid >> 3, q8 = tid & 7;
        float4 v = make_float4(0.f, 0.f, 0.f, 0.f);
        if (s < 31) v = xp4[s * 8 + q8];
        *(float4*)&uRs[s][q8 * 4] = v;
        if (tid < 160) ((float*)sbuf)[tid] = 0.0f;
    }
    __syncthreads();

    // step-invariant write plumbing
    const int wr_dim  = (e < 2) ? (64 + 32 * e + Gq) : (32 * (e - 2) + Gq);
    const int wr_off  = (wr_dim >> 4) * SLP + (wr_dim & 15);
    const bool wr_en   = (e < 4);
    const bool wr_tanh = (e < 2);

    float ybat[8];
    float lastx = 0.0f;
    float4 upref = make_float4(0.f, 0.f, 0.f, 0.f);

    auto dostep = [&](const float* __restrict__ Sr, float* __restrict__ Sw,
                      const float4* __restrict__ urow) -> float {
        const float4* sv4 = (const float4*)(Sr + e * SLP);
        float4 s0 = sv4[0], s1 = sv4[1], s2 = sv4[2], s3 = sv4[3];
        float4 u0 = urow[0], u1 = urow[1];
        float sr[5];
        #pragma unroll
        for (int r = 0; r < 5; ++r) {
            v2f a0 = (v2f){s0.x, s0.y} * wst[r][0] + (v2f){s1.x, s1.y} * wst[r][2];
            v2f a1 = (v2f){s0.z, s0.w} * wst[r][1] + (v2f){s1.z, s1.w} * wst[r][3];
            a0 += (v2f){s2.x, s2.y} * wst[r][4] + (v2f){s3.x, s3.y} * wst[r][6];
            a1 += (v2f){s2.z, s2.w} * wst[r][5] + (v2f){s3.z, s3.w} * wst[r][7];
            a0 += (v2f){u0.x, u0.y} * wu4[r][0] + (v2f){u1.x, u1.y} * wu4[r][2];
            a1 += (v2f){u0.z, u0.w} * wu4[r][1] + (v2f){u1.z, u1.w} * wu4[r][3];
            v2f a = a0 + a1;
            float s = a.x + a.y;
            s = dpp_add<0xB1>(s);     // xor1: quad_perm [1,0,3,2]
            s = dpp_add<0x4E>(s);     // xor2: quad_perm [2,3,0,1]
            s = dpp_add<0x141>(s);    // half-row mirror -> 8-lane all-sum
            sr[r] = s;
        }
        float vA = (e == 0) ? sr[0] : sr[1];
        float vB = (e == 2) ? sr[2] : sr[3];
        float tv = fast_tanh(vA);
        float wval = wr_tanh ? tv : vB;
        if (wr_en) Sw[wr_off] = wval;
        lastx = vB;                    // meaningful for e in {2,3}
        return sr[4];                  // y value (used by e==4 lanes)
    };

    // ---- prologue (step -1): state = 0, u_t = slot31 (0), u_{t+1} = u_0 ----
    // x-cols see only their u_{t+1} weights (= 0 in G) -> write 0; w-cols
    // produce tanh(D21~ u_0); y discarded.  Writes sbuf[1] = S_0.
    {
        const float4* urow = (const float4*)((e < 4) ? &uRs[31][8 * e]
                                                     : &uRs[0][8 * (e - 4)]);
        (void)dostep((const float*)sbuf[0], (float*)sbuf[1], urow);
        step_barrier();
    }

    #pragma unroll 8
    for (int i = 0; i < TT; ++i) {
        const int rp = (i + 1) & 1, wp = i & 1;
        if ((i & 15) == 0) {                   // issue loads for u_{i+16..i+31}
            int t = i + 16 + (tid >> 3);
            if (tid < 128 && t < TT) upref = xp4[t * 8 + (tid & 7)];
        }
        if ((i & 15) == 8) {                   // land u_{i+8..i+23}
            int t = i + 8 + (tid >> 3);
            if (tid < 128 && t < TT) *(float4*)&uRs[t & 31][(tid & 7) * 4] = upref;
        }
        const int ip = i & 31, ic = (i + 1) & 31;
        const float4* urow = (const float4*)((e < 4) ? &uRs[ip][8 * e]
                                                     : &uRs[ic][8 * (e - 4)]);
        float yd = dostep((const float*)sbuf[rp], (float*)sbuf[wp], urow);
        ybat[i & 7] = yd;
        if ((i & 7) == 7 && e == 4) {
            size_t base = yb + (size_t)(i - 7) * NYS + Gq;
            #pragma unroll
            for (int ss = 0; ss < 8; ++ss) out[base + (size_t)ss * NYS] = ybat[ss];
        }
        step_barrier();
    }

    // ---- epilogue: x_final (= x_{TT} computed at step TT-1) ----
    if (e == 2 || e == 3)
        out[xoff + (size_t)b * 64 + wr_dim] = lastx;
}

// ---------------------------------------------------------------------------
extern "C" void kernel_launch(void* const* d_in, const int* in_sizes, int n_in,
                              void* d_out, int out_size, void* d_ws, size_t ws_size,
                              hipStream_t stream) {
    const float* xp  = (const float*)d_in[0];
    const float* Y   = (const float*)d_in[1];
    const float* lam = (const float*)d_in[2];
    const float* A   = (const float*)d_in[3];
    const float* B1  = (const float*)d_in[4];
    const float* B2  = (const float*)d_in[5];
    const float* C1  = (const float*)d_in[6];
    const float* D11 = (const float*)d_in[7];
    const float* D12 = (const float*)d_in[8];
    const float* C2  = (const float*)d_in[9];
    const float* D21 = (const float*)d_in[10];
    float* out = (float*)d_out;
    float* ws  = (float*)d_ws;

    hipLaunchKernelGGL(setup_g_kernel, dim3(1), dim3(1024), 0, stream,
                       Y, lam, A, B1, B2, C1, D11, D12, C2, D21, ws);
    hipLaunchKernelGGL(rnn6_kernel, dim3(BBATCH), dim3(256), 0, stream, xp, ws, out);
}

// Round 7
// 916.678 us; speedup vs baseline: 1.7898x; 1.1970x over previous
//
#include <hip/hip_runtime.h>
#include <cstddef>

#define NXS 64
#define NUS 32
#define NYS 32
#define NWS 64
#define BBATCH 256
#define TT  2048

// ws layout: G[160][192] col-major-by-output: G[c*192 + k]
//   cols c: [0,64) w'(tanh applied), [64,128) x', [128,160) y
//   dims k: [0,64) x, [64,128) w, [128,160) u_t, [160,192) u_{t+1}
// Setup staging: Yinv lives at ws+24576 (y-col region) between setup_inv and
// setup_gxw; setup_y overwrites it last.  Total ws use: 30720 floats.
#define WS_YSTG 24576

typedef float v2f __attribute__((ext_vector_type(2)));

__device__ __forceinline__ float fast_tanh(float x) {
    float e = __expf(2.0f * x);
    return 1.0f - 2.0f * __builtin_amdgcn_rcpf(e + 1.0f);
}

template<int CTRL>
__device__ __forceinline__ float dpp_add(float v) {
    int t = __builtin_amdgcn_update_dpp(0, __float_as_int(v), CTRL, 0xF, 0xF, true);
    return v + __int_as_float(t);
}

// packed fp32 FMA (VOP3P, CDNA2+): acc.lo += x.lo*w.lo ; acc.hi += x.hi*w.hi
__device__ __forceinline__ void pk_fma(v2f& acc, v2f x, v2f w) {
    asm("v_pk_fma_f32 %0, %1, %2, %0" : "+v"(acc) : "v"(x), "v"(w));
}

// barrier draining only LDS (global loads/stores stay in flight)
__device__ __forceinline__ void step_barrier() {
    asm volatile("s_waitcnt lgkmcnt(0)\n\ts_barrier" ::: "memory");
}

// ---------------------------------------------------------------------------
// setup 1/3: Gauss-Jordan Yinv -> ws[WS_YSTG .. +4096)   (1 block)
__global__ __launch_bounds__(1024) void setup_inv_kernel(const float* __restrict__ Y,
                                                         float* __restrict__ ws) {
    __shared__ float M[64 * 129];
    __shared__ float rowk[128];
    __shared__ float ck[64];
    const int tid = threadIdx.x;

    for (int idx = tid; idx < 64 * 64; idx += 1024) {
        int r = idx >> 6, c = idx & 63;
        M[r * 129 + c]      = Y[idx];
        M[r * 129 + 64 + c] = (r == c) ? 1.0f : 0.0f;
    }
    __syncthreads();

    for (int k = 0; k < 64; ++k) {
        float dv = 1.0f / M[k * 129 + k];
        if (tid < 128) rowk[tid] = M[k * 129 + tid] * dv;
        if (tid >= 128 && tid < 192) ck[tid - 128] = M[(tid - 128) * 129 + k];
        __syncthreads();
        for (int idx = tid; idx < 64 * 128; idx += 1024) {
            int r = idx >> 7, c = idx & 127;
            float cur = M[r * 129 + c];
            M[r * 129 + c] = (r == k) ? rowk[c] : cur - ck[r] * rowk[c];
        }
        __syncthreads();
    }
    for (int idx = tid; idx < 4096; idx += 1024) {
        int r = idx >> 6, c = idx & 63;
        ws[WS_YSTG + idx] = M[r * 129 + 64 + c];
    }
}

// ---------------------------------------------------------------------------
// setup 2/3: per-block WxT=[A;B1;B2]~@Yinv in LDS, then write w-cols+x-cols
// of G (24576 floats split over 16 blocks).
__global__ __launch_bounds__(256) void setup_gxw_kernel(const float* __restrict__ lam,
                                                        const float* __restrict__ A,
                                                        const float* __restrict__ B1,
                                                        const float* __restrict__ B2,
                                                        const float* __restrict__ C2,
                                                        const float* __restrict__ D21,
                                                        float* __restrict__ ws) {
    __shared__ float Yi[64 * 64];
    __shared__ float WxT[160 * 64];
    const int tid = threadIdx.x;
    const int bid = blockIdx.x;

    for (int idx = tid; idx < 4096; idx += 256) Yi[idx] = ws[WS_YSTG + idx];
    __syncthreads();

    for (int idx = tid; idx < 10240; idx += 256) {
        int k = idx >> 6, j = idx & 63;
        float s = 0.0f;
        if (k < 64) {
            #pragma unroll 8
            for (int m = 0; m < 64; ++m) s += A[m * 64 + k] * Yi[m * 64 + j];
        } else if (k < 96) {
            int ku = k - 64;
            #pragma unroll 8
            for (int m = 0; m < 64; ++m) s += B1[m * 32 + ku] * Yi[m * 64 + j];
        } else {
            int kw = k - 96;
            #pragma unroll 8
            for (int m = 0; m < 64; ++m) s += B2[m * 64 + kw] * Yi[m * 64 + j];
        }
        WxT[idx] = s;
    }
    __syncthreads();

    // this block's slice of w-cols + x-cols: elements [bid*1536, bid*1536+1536)
    for (int idx = bid * 1536 + tid; idx < bid * 1536 + 1536; idx += 256) {
        int c = idx / 192;
        int k = idx - c * 192;
        int km = (k < 64) ? k : (k < 128) ? (96 + k - 64) : (64 + k - 128);
        float v;
        if (c < 64) {                         // w'-col
            if (k < 160) {
                float s = 0.0f;
                #pragma unroll 8
                for (int m = 0; m < 64; ++m) s += WxT[km * 64 + m] * C2[c * 64 + m];
                v = s / lam[c];
            } else {
                v = D21[c * 32 + (k - 160)] / lam[c];
            }
        } else {                              // x'-col
            int j = c - 64;
            v = (k < 160) ? WxT[km * 64 + j] : 0.0f;
        }
        ws[c * 192 + k] = v;
    }
}

// ---------------------------------------------------------------------------
// setup 3/3: y-cols (no Yinv needed) — overwrites the staging region, runs last.
__global__ __launch_bounds__(256) void setup_y_kernel(const float* __restrict__ C1,
                                                      const float* __restrict__ D11,
                                                      const float* __restrict__ D12,
                                                      float* __restrict__ ws) {
    for (int idx = blockIdx.x * 256 + threadIdx.x; idx < 6144; idx += 16 * 256) {
        int c = 128 + idx / 192;
        int k = idx % 192;
        int j = c - 128;
        float v = (k < 64)  ? C1[j * 64 + k]
                : (k < 128) ? D12[j * 64 + (k - 64)]
                : (k < 160) ? D11[j * 32 + (k - 128)]
                            : 0.0f;
        ws[c * 192 + k] = v;
    }
}

// ---------------------------------------------------------------------------
// Scan v7: 1 chain/block, 512 threads (8 waves -> 2/SIMD for latency overlap,
// grid 256 -> all CUs).  64 groups of 8 lanes: group Gq computes w[Gq] (e==0
// writes tanh) and x[Gq] (e==1 writes); groups <32 (waves 0-3) also y[Gq]
// (e==2 batches).  SIMD s hosts one 3-output wave + one 2-output wave ->
// balanced issue.  K-split 8: lane e owns state dims [16e,16e+16) (4 b128,
// v6-verified SLP=20 banking) + 8 u dims (1..2 b128 from 36-pad ring).
// Inner product: 12 x v_pk_fma_f32 (asm) per output; reduce: 3 DPP levels.
__global__ __launch_bounds__(512, 2) void rnn7_kernel(const float* __restrict__ xp,
                                                      const float* __restrict__ ws,
                                                      float* __restrict__ out) {
    const int b   = blockIdx.x;
    const int tid = threadIdx.x;

    __shared__ __align__(16) float sbuf[2][160];
    __shared__ __align__(16) float uRs[32][36];

    const float4* __restrict__ xp4 = (const float4*)(xp + (size_t)b * (TT * NUS));
    const size_t yb   = (size_t)b * (TT * NYS);
    const size_t xoff = (size_t)BBATCH * TT * NYS;

    // ---- init: u slots 0..30 = u_0..30, slot 31 = 0 (u_{-1}); sbuf[0] = 0 --
    if (tid < 256) {
        int s = tid >> 3, q8 = tid & 7;
        float4 v = make_float4(0.f, 0.f, 0.f, 0.f);
        if (s < 31) v = xp4[s * 8 + q8];
        *(float4*)&uRs[s][q8 * 4] = v;
    }
    if (tid < 160) sbuf[0][tid] = 0.0f;
    __syncthreads();

    const int e  = tid & 7;
    const int Gq = tid >> 3;                       // [0,64)

    // ---- weights: NOUT outputs x 12 v2f (8 state + 4 u) ----
    const int NOUT = (Gq < 32) ? 3 : 2;            // wave-uniform
    v2f w[3][12];
    #pragma unroll
    for (int r = 0; r < 3; ++r) {
        if (r >= NOUT) break;
        const int col = (r == 0) ? Gq : (r == 1) ? (64 + Gq) : (128 + Gq);
        const float* Gc = ws + (size_t)col * 192;
        const float* sb = Gc + 16 * e;
        #pragma unroll
        for (int k = 0; k < 4; ++k) {
            float4 gv = *(const float4*)(sb + 4 * k);
            w[r][2 * k]     = (v2f){gv.x, gv.y};
            w[r][2 * k + 1] = (v2f){gv.z, gv.w};
        }
        const float* ub = Gc + ((e < 4) ? (128 + 8 * e) : (160 + 8 * (e - 4)));
        #pragma unroll
        for (int t = 0; t < 2; ++t) {
            float4 gv = *(const float4*)(ub + 4 * t);
            w[r][8 + 2 * t] = (v2f){gv.x, gv.y};
            w[r][9 + 2 * t] = (v2f){gv.z, gv.w};
        }
    }

    const int wr_off = (e == 0) ? (((64 + Gq) >> 4) * 20 + ((64 + Gq) & 15))
                                : ((Gq >> 4) * 20 + (Gq & 15));

    float ybat[8];
    float lastx = 0.0f;
    float4 upref = make_float4(0.f, 0.f, 0.f, 0.f);

    auto dostep = [&](int rb, int wb, int ip, int ic,
                      float& s0o, float& s1o, float& s2o) {
        const float4* sv4 = (const float4*)(&sbuf[rb][0] + e * 20);
        float4 s0 = sv4[0], s1 = sv4[1], s2 = sv4[2], s3 = sv4[3];
        const float4* uu = (const float4*)&uRs[(e < 4) ? ip : ic][8 * (e & 3)];
        float4 u0 = uu[0], u1 = uu[1];
        v2f sv[12] = {{s0.x, s0.y}, {s0.z, s0.w}, {s1.x, s1.y}, {s1.z, s1.w},
                      {s2.x, s2.y}, {s2.z, s2.w}, {s3.x, s3.y}, {s3.z, s3.w},
                      {u0.x, u0.y}, {u0.z, u0.w}, {u1.x, u1.y}, {u1.z, u1.w}};
        float sr[3] = {0.f, 0.f, 0.f};
        #pragma unroll
        for (int r = 0; r < 3; ++r) {
            if (r >= NOUT) break;
            v2f acc = (v2f){0.f, 0.f};
            #pragma unroll
            for (int k = 0; k < 12; ++k) pk_fma(acc, sv[k], w[r][k]);
            float s = acc.x + acc.y;
            s = dpp_add<0xB1>(s);      // xor1
            s = dpp_add<0x4E>(s);      // xor2
            s = dpp_add<0x141>(s);     // row_half_mirror -> 8-lane all-sum
            sr[r] = s;
        }
        if (e < 2) {
            float val = (e == 0) ? fast_tanh(sr[0]) : sr[1];
            sbuf[wb][wr_off] = val;
        }
        s0o = sr[0]; s1o = sr[1]; s2o = sr[2];
    };

    // ---- prologue: S_0 from zero state; u_t = slot31(0), u_{t+1} = u_0 ----
    {
        float a, bv, c;
        dostep(0, 1, 31, 0, a, bv, c);
    }
    step_barrier();

    #pragma unroll 8
    for (int i = 0; i < TT; ++i) {
        const int rp = (i + 1) & 1, wp = i & 1;
        if ((i & 15) == 0) {                   // issue loads for u_{i+16..i+31}
            int t = i + 16 + (tid >> 3);
            if (tid < 128 && t < TT) upref = xp4[t * 8 + (tid & 7)];
        }
        if ((i & 15) == 8) {                   // land u_{i+8..i+23}
            int t = i + 8 + (tid >> 3);
            if (tid < 128 && t < TT) *(float4*)&uRs[t & 31][(tid & 7) * 4] = upref;
        }
        float sr0, sr1, sr2;
        dostep(rp, wp, i & 31, (i + 1) & 31, sr0, sr1, sr2);
        lastx = sr1;
        if (NOUT == 3 && e == 2) {
            ybat[i & 7] = sr2;
            if ((i & 7) == 7) {
                size_t base = yb + (size_t)(i - 7) * NYS + Gq;
                #pragma unroll
                for (int ss = 0; ss < 8; ++ss) out[base + (size_t)ss * NYS] = ybat[ss];
            }
        }
        step_barrier();
    }

    // ---- epilogue: x_final = x_{TT} (computed at i = TT-1) ----
    if (e == 1) out[xoff + (size_t)b * 64 + Gq] = lastx;
}

// ---------------------------------------------------------------------------
extern "C" void kernel_launch(void* const* d_in, const int* in_sizes, int n_in,
                              void* d_out, int out_size, void* d_ws, size_t ws_size,
                              hipStream_t stream) {
    const float* xp  = (const float*)d_in[0];
    const float* Y   = (const float*)d_in[1];
    const float* lam = (const float*)d_in[2];
    const float* A   = (const float*)d_in[3];
    const float* B1  = (const float*)d_in[4];
    const float* B2  = (const float*)d_in[5];
    const float* C1  = (const float*)d_in[6];
    const float* D11 = (const float*)d_in[7];
    const float* D12 = (const float*)d_in[8];
    const float* C2  = (const float*)d_in[9];
    const float* D21 = (const float*)d_in[10];
    float* out = (float*)d_out;
    float* ws  = (float*)d_ws;

    hipLaunchKernelGGL(setup_inv_kernel, dim3(1),  dim3(1024), 0, stream, Y, ws);
    hipLaunchKernelGGL(setup_gxw_kernel, dim3(16), dim3(256),  0, stream,
                       lam, A, B1, B2, C2, D21, ws);
    hipLaunchKernelGGL(setup_y_kernel,   dim3(16), dim3(256),  0, stream,
                       C1, D11, D12, ws);
    hipLaunchKernelGGL(rnn7_kernel, dim3(BBATCH), dim3(512), 0, stream, xp, ws, out);
}